// Round 5
// baseline (656.948 us; speedup 1.0000x reference)
//
#include <hip/hip_runtime.h>

#define Tt 128
#define Nn 2048
#define Hh 128
#define Dd 128
#define NB 4          // batch rows per block
#define LDA 136       // bf16 LDS row stride (shorts): 128 + 8 pad (16B-aligned rows)
#define LDG 388       // fp32 LDS row stride (dwords): 384 + 4 pad

// workspace layout (floats)
#define WC_OFF  0            // Wc  = Wih@W2@W1   (384 x 128)
#define BC_OFF  49152        // bc  = Wih@(W2@b1+b2)+bih  (384)
#define TMP_OFF 49536        // Tmp = W2@W1       (128 x 128)
#define BT_OFF  65920        // bt  = W2@b1+b2    (128)

typedef __attribute__((ext_vector_type(8))) short v8s;
typedef __attribute__((ext_vector_type(4))) float v4f;

__device__ __forceinline__ unsigned short f2bf(float f) {
    unsigned int u = __builtin_bit_cast(unsigned int, f);
    u += 0x7FFFu + ((u >> 16) & 1u);   // round-to-nearest-even
    return (unsigned short)(u >> 16);
}

__device__ __forceinline__ v4f mfma_bf(v8s a, v8s b, v4f c) {
    return __builtin_amdgcn_mfma_f32_16x16x32_bf16(a, b, c, 0, 0, 0);
}

__device__ __forceinline__ v8s load_wfrag_bf(const float* __restrict__ W, int row, int k0) {
    const v4f* p = (const v4f*)(W + row * 128 + k0);
    v4f a = p[0], b = p[1];
    v8s r;
    r[0] = (short)f2bf(a[0]); r[1] = (short)f2bf(a[1]);
    r[2] = (short)f2bf(a[2]); r[3] = (short)f2bf(a[3]);
    r[4] = (short)f2bf(b[0]); r[5] = (short)f2bf(b[1]);
    r[6] = (short)f2bf(b[2]); r[7] = (short)f2bf(b[3]);
    return r;
}

__device__ __forceinline__ void store_bf4(unsigned short* p, v4f v) {
    unsigned int lo = ((unsigned int)f2bf(v[1]) << 16) | (unsigned int)f2bf(v[0]);
    unsigned int hi = ((unsigned int)f2bf(v[3]) << 16) | (unsigned int)f2bf(v[2]);
    uint2 d; d.x = lo; d.y = hi;
    *(uint2*)p = d;   // 8B aligned (col4*2 bytes is a multiple of 8)
}

__device__ __forceinline__ float sigm(float x)  { return __frcp_rn(1.f + __expf(-x)); }
__device__ __forceinline__ float tanh_f(float x){ return 2.f * __frcp_rn(1.f + __expf(-2.f * x)) - 1.f; }

// drain own LDS ops only; out-stores / x-prefetch stay in flight across barriers
#define BARRIER() asm volatile("s_waitcnt lgkmcnt(0)\n\ts_barrier" ::: "memory")

// ---------- prep (round-1 verbatim, two launches) ----------
__global__ void prep_tmp(const float* __restrict__ W1, const float* __restrict__ b1,
                         const float* __restrict__ W2, const float* __restrict__ b2,
                         float* __restrict__ ws) {
    float* Tmp = ws + TMP_OFF;
    float* bt  = ws + BT_OFF;
    int j = blockIdx.x, d = threadIdx.x;
    float acc = 0.f;
    for (int k = 0; k < 128; ++k) acc += W2[j * 128 + k] * W1[k * 128 + d];
    Tmp[j * 128 + d] = acc;
    if (d == 0) {
        float s = 0.f;
        for (int k = 0; k < 128; ++k) s += W2[j * 128 + k] * b1[k];
        bt[j] = s + b2[j];
    }
}

__global__ void prep_wc(const float* __restrict__ Wih, const float* __restrict__ bih,
                        float* __restrict__ ws) {
    const float* Tmp = ws + TMP_OFF;
    const float* bt  = ws + BT_OFF;
    float* Wc = ws + WC_OFF;
    float* bc = ws + BC_OFF;
    int r = blockIdx.x, d = threadIdx.x;
    float acc = 0.f;
    for (int j = 0; j < 128; ++j) acc += Wih[r * 128 + j] * Tmp[j * 128 + d];
    Wc[r * 128 + d] = acc;
    if (d == 0) {
        float s = 0.f;
        for (int j = 0; j < 128; ++j) s += Wih[r * 128 + j] * bt[j];
        bc[r] = s + bih[r];
    }
}

// ---------- main scan: NB=4, grid 512, 8 waves, 2 barriers/step ----------
// Shared 8-row A-buffer: rows 0-3 = LN1(x_t) (batch rows 0-3), rows 4-7 = masked h.
// Seg A (round-1 32-lane-group mapping, each row written by exactly ONE group):
//   groups 0-3  (waves 0,1): LN1 row g      -> abuf row g
//   groups 8-11 (waves 4,5): GRU tail row g-8, LN2, out; h -> abuf row 4+(g-8)
//   groups 4-7, 12-15: idle in seg A
// Seg B (round-1 verbatim, arow = l16&7, both quads store):
//   P waves 0-3: D = A@Wc^T ; D rows 0-3 (quad0) = gi -> gibuf
//   Q waves 4-7: D = A@Whh^T; D rows 4-7 (quad1) = gh -> ghbuf
__global__ __launch_bounds__(512, 2)
void rppo_scan(const float* __restrict__ x, const float* __restrict__ hxs,
               const float* __restrict__ masks,
               const float* __restrict__ ln1_w, const float* __restrict__ ln1_b,
               const float* __restrict__ Whh, const float* __restrict__ bhh,
               const float* __restrict__ ln2_w, const float* __restrict__ ln2_b,
               const float* __restrict__ ws, float* __restrict__ out)
{
    __shared__ unsigned short abuf[8 * LDA];    // rows 0-3: LN1 out, rows 4-7: masked h
    __shared__ float gibuf[NB * LDG];           // gi(t) + bc
    __shared__ float ghbuf[NB * LDG];           // gh(t) + bhh
    __shared__ float mbuf[Tt * NB];             // this block's masks

    const int tid  = threadIdx.x;
    const int wave = tid >> 6;
    const int lane = tid & 63;
    const int l16  = lane & 15;
    const int quad = lane >> 4;
    const int arow = l16 & 7;
    const int wsub = wave & 3;
    const bool isP = (wave < 4);
    const int n0   = blockIdx.x * NB;

    const float* Wc = ws + WC_OFF;
    const float* bc = ws + BC_OFF;

    // ---- weight fragments: 24 frags / wave ----
    v8s wreg[6][4];
    float brC[6];
    {
        const float* Wm = isP ? Wc : Whh;
        const float* bm = isP ? bc : bhh;
#pragma unroll
        for (int c = 0; c < 6; ++c) {
            int rowc = (6 * wsub + c) * 16 + l16;
            brC[c] = bm[rowc];
#pragma unroll
            for (int kk = 0; kk < 4; ++kk)
                wreg[c][kk] = load_wfrag_bf(Wm, rowc, kk * 32 + quad * 8);
        }
    }

    // masks for this block (one element per thread; Tt*NB == 512)
    {
        int t = tid >> 2, b = tid & 3;
        mbuf[tid] = masks[t * Nn + n0 + b];
    }

    // ---- seg-A roles: round-1 32-lane-group mapping, no duplicate writers ----
    const int g      = tid >> 5;                  // 32-lane group 0..15
    const bool doLN  = (g < 4);                   // waves 0,1
    const bool doTl  = (g >= 8) && (g < 12);      // waves 4,5
    const int brow   = doLN ? g : (g - 8);        // batch row 0..3 (idle: unused)
    const int col4   = (lane & 31) << 2;

    v4f lnw = {0.f,0.f,0.f,0.f}, lnb = {0.f,0.f,0.f,0.f}, hx = {0.f,0.f,0.f,0.f};
    if (doLN) {
        lnw = *(const v4f*)(ln1_w + col4);
        lnb = *(const v4f*)(ln1_b + col4);
        hx  = *(const v4f*)(x + (size_t)(n0 + brow) * Dd + col4);   // t=0 prefetch
    } else if (doTl) {
        lnw = *(const v4f*)(ln2_w + col4);
        lnb = *(const v4f*)(ln2_b + col4);
        hx  = *(const v4f*)(hxs + (size_t)(n0 + brow) * Hh + col4);
        float m0 = masks[n0 + brow];
#pragma unroll
        for (int e = 0; e < 4; ++e) hx[e] *= m0;
        store_bf4(abuf + (4 + brow) * LDA + col4, hx);
    }
    __syncthreads();

    for (int i = 0; i <= Tt; ++i) {
        // ===== seg A =====
        if (doLN) {
            if (i < Tt) {
                float s  = hx[0] + hx[1] + hx[2] + hx[3];
                float ss = hx[0]*hx[0] + hx[1]*hx[1] + hx[2]*hx[2] + hx[3]*hx[3];
#pragma unroll
                for (int m = 1; m < 32; m <<= 1) {
                    s  += __shfl_xor(s,  m, 64);
                    ss += __shfl_xor(ss, m, 64);
                }
                float mu = s * (1.f / 128.f);
                float rs = __frsqrt_rn(ss * (1.f / 128.f) - mu * mu + 1e-5f);
                v4f f;
#pragma unroll
                for (int e = 0; e < 4; ++e) f[e] = (hx[e] - mu) * rs * lnw[e] + lnb[e];
                store_bf4(abuf + brow * LDA + col4, f);
                if (i + 1 < Tt)
                    hx = *(const v4f*)(x + ((size_t)(i + 1) * Nn + n0 + brow) * Dd + col4);
            }
        } else if (doTl && i >= 1) {
            const int t = i - 1;
            const float* gb = gibuf + brow * LDG + col4;
            const float* hb = ghbuf + brow * LDG + col4;
            v4f ir  = *(const v4f*)(gb);
            v4f iz  = *(const v4f*)(gb + 128);
            v4f inn = *(const v4f*)(gb + 256);
            v4f hr  = *(const v4f*)(hb);
            v4f hz  = *(const v4f*)(hb + 128);
            v4f hn  = *(const v4f*)(hb + 256);
            v4f hnew;
#pragma unroll
            for (int e = 0; e < 4; ++e) {
                float rg = sigm(ir[e] + hr[e]);
                float z  = sigm(iz[e] + hz[e]);
                float n  = tanh_f(inn[e] + rg * hn[e]);
                hnew[e] = n + z * (hx[e] - n);   // (1-z)*n + z*h
            }
            float s2  = hnew[0] + hnew[1] + hnew[2] + hnew[3];
            float ss2 = hnew[0]*hnew[0] + hnew[1]*hnew[1] + hnew[2]*hnew[2] + hnew[3]*hnew[3];
#pragma unroll
            for (int m = 1; m < 32; m <<= 1) {
                s2  += __shfl_xor(s2,  m, 64);
                ss2 += __shfl_xor(ss2, m, 64);
            }
            float mu2 = s2 * (1.f / 128.f);
            float rs2 = __frsqrt_rn(ss2 * (1.f / 128.f) - mu2 * mu2 + 1e-5f);
            v4f o;
#pragma unroll
            for (int e = 0; e < 4; ++e) o[e] = (hnew[e] - mu2) * rs2 * lnw[e] + lnb[e];
            *(v4f*)(out + ((size_t)t * Nn + n0 + brow) * Hh + col4) = o;

            if (t + 1 < Tt) {
                float mt = mbuf[(t + 1) * NB + brow];
#pragma unroll
                for (int e = 0; e < 4; ++e) hx[e] = hnew[e] * mt;
                store_bf4(abuf + (4 + brow) * LDA + col4, hx);
            } else {
                *(v4f*)(out + (size_t)Tt * Nn * Hh + (size_t)(n0 + brow) * Hh + col4) = hnew;
            }
        }
        BARRIER();   // B1

        // ===== seg B: shared A (rows 0-3 LN1, rows 4-7 h); P->gi, Q->gh =====
        if (i < Tt) {
            v8s af[4];
#pragma unroll
            for (int kk = 0; kk < 4; ++kk)
                af[kk] = *(const v8s*)(abuf + arow * LDA + kk * 32 + quad * 8);
            v4f acc[6];
#pragma unroll
            for (int c = 0; c < 6; ++c) acc[c] = (v4f){0.f, 0.f, 0.f, 0.f};
#pragma unroll
            for (int c = 0; c < 6; ++c)
#pragma unroll
                for (int kk = 0; kk < 4; ++kk)
                    acc[c] = mfma_bf(af[kk], wreg[c][kk], acc[c]);
            // D row = quad*4+rr.  P: rows 0-3 = LN1@Wc = gi.  Q: rows 4-7 = h@Whh = gh.
            if (isP) {
                if (quad == 0) {
#pragma unroll
                    for (int c = 0; c < 6; ++c) {
                        int col = (6 * wsub + c) * 16 + l16;
#pragma unroll
                        for (int rr = 0; rr < 4; ++rr)
                            gibuf[rr * LDG + col] = acc[c][rr] + brC[c];
                    }
                }
            } else {
                if (quad == 1) {
#pragma unroll
                    for (int c = 0; c < 6; ++c) {
                        int col = (6 * wsub + c) * 16 + l16;
#pragma unroll
                        for (int rr = 0; rr < 4; ++rr)
                            ghbuf[rr * LDG + col] = acc[c][rr] + brC[c];
                    }
                }
            }
        }
        BARRIER();   // B2
    }
}

extern "C" void kernel_launch(void* const* d_in, const int* in_sizes, int n_in,
                              void* d_out, int out_size, void* d_ws, size_t ws_size,
                              hipStream_t stream) {
    const float* x     = (const float*)d_in[0];
    const float* hxs   = (const float*)d_in[1];
    const float* masks = (const float*)d_in[2];
    const float* ln1w  = (const float*)d_in[3];
    const float* ln1b  = (const float*)d_in[4];
    const float* W1    = (const float*)d_in[5];
    const float* b1    = (const float*)d_in[6];
    const float* W2    = (const float*)d_in[7];
    const float* b2    = (const float*)d_in[8];
    const float* Wih   = (const float*)d_in[9];
    const float* bih   = (const float*)d_in[10];
    const float* Whh   = (const float*)d_in[11];
    const float* bhh   = (const float*)d_in[12];
    const float* ln2w  = (const float*)d_in[13];
    const float* ln2b  = (const float*)d_in[14];
    float* out = (float*)d_out;
    float* ws  = (float*)d_ws;

    hipLaunchKernelGGL(prep_tmp, dim3(128), dim3(128), 0, stream, W1, b1, W2, b2, ws);
    hipLaunchKernelGGL(prep_wc,  dim3(384), dim3(128), 0, stream, Wih, bih, ws);

    hipLaunchKernelGGL(rppo_scan, dim3(Nn / NB), dim3(512), 0, stream,
                       x, hxs, masks, ln1w, ln1b, Whh, bhh, ln2w, ln2b,
                       (const float*)ws, out);
}